// Round 10
// baseline (193.045 us; speedup 1.0000x reference)
//
#include <hip/hip_runtime.h>
#include <hip/hip_cooperative_groups.h>
#include <math.h>

namespace cg = cooperative_groups;

#define NN 1000000
#define NF4 5000000       // NN*5 float4s in Memory
#define WD 20
#define NB 977            // blocks of 1024 rows
#define PST 1024          // pnrhT column stride
#define CB 160            // cooperative grid blocks

// d_out layout (floats): out[325] | rw[NN] | ww[NN] | new_memory[NN*20] | nrh[20]
#define OUT_OFF 0
#define RW_OFF  325
#define WW_OFF  1000325
#define NM_OFF  2000325
#define NRH_OFF 22000325

__device__ __forceinline__ float sigmoidf_(float x){ return 1.0f/(1.0f+expf(-x)); }
__device__ __forceinline__ float softplusf_(float x){ return (x>30.f)?x:log1pf(expf(x)); }

// ------- K1: controller-head prologue (redundant per block) + cosine scores -------
// P layout: kr:0-19 gr:20 sr:21-23 gammar:24 betar:25 knr:26
//           kw:32-51 gw:52 sw:53-55 gammaw:56 betaw:57 knw:58
//           erase:64-83 addraw:84-103 rho:104 ah0:105 ah1:106 addf:112-131
__global__ __launch_bounds__(256) void k_scores(
    const float* __restrict__ X,
    const float* __restrict__ W1, const float* __restrict__ b1,
    const float* __restrict__ W2, const float* __restrict__ b2,
    const float* __restrict__ Wxi, const float* __restrict__ bxi,
    const float* __restrict__ Wz, const float* __restrict__ bz,
    const float* __restrict__ M, float* __restrict__ Pg,
    float2* __restrict__ sc2, float4* __restrict__ pms){
  __shared__ float4 ld[1280];   // 20 KB
  __shared__ float h1[48], h2[72], xi[95], sP[132];
  int t=threadIdx.x, b=blockIdx.x;
  if(t<48){ float a=b1[t]; const float* w=W1+t*14; for(int c=0;c<14;c++) a+=X[c]*w[c]; h1[t]=a; }
  __syncthreads();
  if(t<72){ float a=b2[t]; const float* w=W2+t*48; for(int c=0;c<48;c++) a+=h1[c]*w[c]; h2[t]=a; }
  __syncthreads();
  if(t<92){ float a=bxi[t]; const float* w=Wxi+t*72; for(int c=0;c<72;c++) a+=h2[c]*w[c]; xi[t]=a; }
  else if(t<95){ int z=t-92; float a=bz[z]; const float* w=Wz+z*72; for(int c=0;c<72;c++) a+=h2[c]*w[c]; xi[92+z]=a; }
  __syncthreads();
  if(t<20){
    sP[0+t]  = tanhf(xi[t]);
    sP[32+t] = tanhf(xi[26+t]);
    sP[64+t] = sigmoidf_(xi[52+t]);
    sP[84+t] = tanhf(xi[72+t]);
  }
  __syncthreads();
  if(t==32){   // read-head scalars (wave 0)
    float g=sigmoidf_(xi[20]);
    float a0=xi[21],a1=xi[22],a2=xi[23];
    float mx=fmaxf(a0,fmaxf(a1,a2));
    float e0=expf(a0-mx),e1=expf(a1-mx),e2=expf(a2-mx),es=e0+e1+e2;
    float gamma=1.0f+softplusf_(xi[24]);
    float beta=softplusf_(xi[25]);
    float n2=0.f;
#pragma unroll
    for(int j=0;j<20;j++){ float ke=sP[j]+1e-16f; n2+=ke*ke; }
    sP[20]=g; sP[21]=e0/es; sP[22]=e1/es; sP[23]=e2/es; sP[24]=gamma; sP[25]=beta;
    sP[26]=fmaxf(sqrtf(n2),1e-8f);
  }
  if(t==96){   // write-head scalars (wave 1)
    float g=sigmoidf_(xi[46]);
    float a0=xi[47],a1=xi[48],a2=xi[49];
    float mx=fmaxf(a0,fmaxf(a1,a2));
    float e0=expf(a0-mx),e1=expf(a1-mx),e2=expf(a2-mx),es=e0+e1+e2;
    float gamma=1.0f+softplusf_(xi[50]);
    float beta=softplusf_(xi[51]);
    float n2=0.f;
#pragma unroll
    for(int j=0;j<20;j++){ float ke=sP[32+j]+1e-16f; n2+=ke*ke; }
    sP[52]=g; sP[53]=e0/es; sP[54]=e1/es; sP[55]=e2/es; sP[56]=gamma; sP[57]=beta;
    sP[58]=fmaxf(sqrtf(n2),1e-8f);
  }
  if(t==160){  // zeta scalars (wave 2)
    sP[104]=sigmoidf_(xi[92]);
    float mx=fmaxf(xi[93],xi[94]);
    float e1=expf(xi[93]-mx), e2=expf(xi[94]-mx);
    sP[105]=e1/(e1+e2); sP[106]=e2/(e1+e2);
  }
  __syncthreads();
  if(b==0 && t<132) Pg[t]=sP[t];
  float kr[20], kw[20];
#pragma unroll
  for(int j=0;j<20;j++){ kr[j]=sP[j]+1e-16f; kw[j]=sP[32+j]+1e-16f; }
  float betar=sP[25], betaw=sP[57], knr=sP[26], knw=sP[58];
  const float4* Mf4=(const float4*)M;
  float sR[4], sW[4];
  for(int p=0;p<4;p++){
    int rb=b*1024+p*256;
    size_t f4b=(size_t)rb*5;
#pragma unroll
    for(int k=0;k<5;k++){
      size_t idx=f4b+(size_t)(k*256+t);
      ld[k*256+t] = (idx<NF4)?Mf4[idx]:make_float4(0.f,0.f,0.f,0.f);
    }
    __syncthreads();
    int i=rb+t;
    float srv=-3.0e38f, swv=-3.0e38f;
    if(i<NN){
      float dr=0.f,dw=0.f,n2=0.f;
#pragma unroll
      for(int q=0;q<5;q++){
        float4 v=ld[t*5+q];
        float m0=v.x+1e-16f,m1=v.y+1e-16f,m2=v.z+1e-16f,m3=v.w+1e-16f;
        dr+=m0*kr[4*q]+m1*kr[4*q+1]+m2*kr[4*q+2]+m3*kr[4*q+3];
        dw+=m0*kw[4*q]+m1*kw[4*q+1]+m2*kw[4*q+2]+m3*kw[4*q+3];
        n2+=m0*m0+m1*m1+m2*m2+m3*m3;
      }
      float nm=fmaxf(sqrtf(n2),1e-8f);
      srv=betar*(dr/(nm*knr));
      swv=betaw*(dw/(nm*knw));
      sc2[i]=make_float2(srv,swv);
    }
    sR[p]=srv; sW[p]=swv;
    __syncthreads();
  }
  float* r1=(float*)ld; float* r2=r1+256;
  double* d1=(double*)(r1+512); double* d2=d1+256;
  float lm1=fmaxf(fmaxf(sR[0],sR[1]),fmaxf(sR[2],sR[3]));
  float lm2=fmaxf(fmaxf(sW[0],sW[1]),fmaxf(sW[2],sW[3]));
  r1[t]=lm1; r2[t]=lm2; __syncthreads();
  for(int o=128;o>0;o>>=1){ if(t<o){ r1[t]=fmaxf(r1[t],r1[t+o]); r2[t]=fmaxf(r2[t],r2[t+o]); } __syncthreads(); }
  float mb1=r1[0], mb2=r2[0]; __syncthreads();
  double s1=0.0,s2=0.0;
#pragma unroll
  for(int p=0;p<4;p++){ s1+=(double)expf(sR[p]-mb1); s2+=(double)expf(sW[p]-mb2); }
  d1[t]=s1; d2[t]=s2; __syncthreads();
  for(int o=128;o>0;o>>=1){ if(t<o){ d1[t]+=d1[t+o]; d2[t]+=d2[t+o]; } __syncthreads(); }
  if(t==0) pms[b]=make_float4(mb1,mb2,(float)d1[0],(float)d2[0]);
}

// ------- K2: interpolate+shift+pow; fused rw@M; per-block partial stores -------
__global__ __launch_bounds__(256) void k_shift(const float2* __restrict__ sc2,
                        const float* __restrict__ wpr, const float* __restrict__ wpw,
                        const float* __restrict__ M, const float* __restrict__ P,
                        const float4* __restrict__ pms,
                        float* __restrict__ w_r_out, float* __restrict__ w_w_out,
                        double* __restrict__ pZ, double* __restrict__ pnrhT){
  __shared__ float4 ld[1280];
  __shared__ float bmS[4];
  float* r1=(float*)ld; float* r2=r1+256;
  double* d1=(double*)(r1+512); double* d2=d1+256;
  float* wsum=(float*)(d2+256);  // [4][20]
  int t=threadIdx.x, b=blockIdx.x;
  float4 v4[4];
#pragma unroll
  for(int k=0;k<4;k++){
    int idx=t+k*256;
    v4[k] = (idx<NB) ? pms[idx] : make_float4(-3.0e38f,-3.0e38f,0.f,0.f);
  }
  float lm1=fmaxf(fmaxf(v4[0].x,v4[1].x),fmaxf(v4[2].x,v4[3].x));
  float lm2=fmaxf(fmaxf(v4[0].y,v4[1].y),fmaxf(v4[2].y,v4[3].y));
  r1[t]=lm1; r2[t]=lm2; __syncthreads();
  for(int o=128;o>0;o>>=1){ if(t<o){ r1[t]=fmaxf(r1[t],r1[t+o]); r2[t]=fmaxf(r2[t],r2[t+o]); } __syncthreads(); }
  if(t==0){ bmS[0]=r1[0]; bmS[1]=r2[0]; } __syncthreads();
  float mr=bmS[0], mw=bmS[1];
  double s1=0.0,s2=0.0;
#pragma unroll
  for(int k=0;k<4;k++){
    s1 += (double)v4[k].z * (double)expf(v4[k].x-mr);
    s2 += (double)v4[k].w * (double)expf(v4[k].y-mw);
  }
  d1[t]=s1; d2[t]=s2; __syncthreads();
  for(int o=128;o>0;o>>=1){ if(t<o){ d1[t]+=d1[t+o]; d2[t]+=d2[t+o]; } __syncthreads(); }
  if(t==0){ bmS[2]=(float)d1[0]; bmS[3]=(float)d2[0]; } __syncthreads();
  float Sr=bmS[2], Sw=bmS[3];
  float gr=P[20], s0r=P[21], s1r=P[22], s2r=P[23], gar=P[24];
  float gw=P[52], s0w=P[53], s1w=P[54], s2w=P[55], gaw=P[56];
  float omgr=1.0f-gr, omgw=1.0f-gw;
  const float4* Mf4=(const float4*)M;
  float acc[20];
#pragma unroll
  for(int j=0;j<20;j++) acc[j]=0.f;
  double zr=0.0, zw=0.0;
  for(int p=0;p<4;p++){
    int rb=b*1024+p*256;
    size_t f4b=(size_t)rb*5;
#pragma unroll
    for(int k=0;k<5;k++){
      size_t idx=f4b+(size_t)(k*256+t);
      ld[k*256+t] = (idx<NF4)?Mf4[idx]:make_float4(0.f,0.f,0.f,0.f);
    }
    __syncthreads();
    int i=rb+t;
    if(i<NN){
      int im1=(i==0)?(NN-1):(i-1);
      int ip1=(i==NN-1)?0:(i+1);
      float2 scm=sc2[im1], sc0=sc2[i], scp=sc2[ip1];
      float wgrm = gr*(expf(scm.x-mr)/Sr) + omgr*wpr[im1];
      float wgr0 = gr*(expf(sc0.x-mr)/Sr) + omgr*wpr[i  ];
      float wgrp = gr*(expf(scp.x-mr)/Sr) + omgr*wpr[ip1];
      float wgwm = gw*(expf(scm.y-mw)/Sw) + omgw*wpw[im1];
      float wgw0 = gw*(expf(sc0.y-mw)/Sw) + omgw*wpw[i  ];
      float wgwp = gw*(expf(scp.y-mw)/Sw) + omgw*wpw[ip1];
      float wr = powf(s0r*wgrm + s1r*wgr0 + s2r*wgrp, gar);
      float ww = powf(s0w*wgwm + s1w*wgw0 + s2w*wgwp, gaw);
      w_r_out[i]=wr; w_w_out[i]=ww;
      zr+=(double)wr; zw+=(double)ww;
#pragma unroll
      for(int q=0;q<5;q++){
        float4 mv=ld[t*5+q];
        acc[4*q+0]+=wr*mv.x; acc[4*q+1]+=wr*mv.y; acc[4*q+2]+=wr*mv.z; acc[4*q+3]+=wr*mv.w;
      }
    }
    __syncthreads();
  }
  d1[t]=zr; d2[t]=zw; __syncthreads();
  for(int o=128;o>0;o>>=1){ if(t<o){ d1[t]+=d1[t+o]; d2[t]+=d2[t+o]; } __syncthreads(); }
  if(t==0){ pZ[2*b]=d1[0]; pZ[2*b+1]=d2[0]; }
  __syncthreads();
#pragma unroll
  for(int j=0;j<20;j++){
    for(int off=32;off>0;off>>=1) acc[j]+=__shfl_down(acc[j],off,64);
  }
  int wave=t>>6, lane=t&63;
  if(lane==0){
#pragma unroll
    for(int j=0;j<20;j++) wsum[wave*20+j]=acc[j];
  }
  __syncthreads();
  if(t<20){
    double s=(double)wsum[0*20+t]+(double)wsum[1*20+t]+(double)wsum[2*20+t]+(double)wsum[3*20+t];
    pnrhT[(size_t)t*PST+b]=s;
  }
}

// ------- K3: cooperative tail — reduce + L1..L4 + fin, grid.sync between phases -------
__global__ __launch_bounds__(256) void k_coop(
    const double* __restrict__ pZ, const double* __restrict__ pnrhT,
    const float* __restrict__ rhd,
    const float* __restrict__ aW1,const float* __restrict__ ab1,
    const float* __restrict__ mW1,const float* __restrict__ mb1,
    const float* __restrict__ aW2,const float* __restrict__ ab2,
    const float* __restrict__ mW2,const float* __restrict__ mb2,
    const float* __restrict__ aW3,const float* __restrict__ ab3,
    const float* __restrict__ mW3,const float* __restrict__ mb3,
    const float* __restrict__ aW4,const float* __restrict__ ab4,
    const float* __restrict__ mW4,const float* __restrict__ mb4,
    const float* __restrict__ Wv, const float* __restrict__ bv,
    float* __restrict__ P, float* __restrict__ out,
    double* __restrict__ Sd, double* __restrict__ nrhraw,
    float* __restrict__ h1g, float* __restrict__ h2g,
    float* __restrict__ h3g, float* __restrict__ h4g){
  cg::grid_group grid = cg::this_grid();
  __shared__ double dd[256];
  __shared__ float in40[40];
  __shared__ float red[256], sc[2];
  int t=threadIdx.x, b=blockIdx.x, wave=t>>6, lane=t&63;
  int wid=b*4+wave;
  // P0: blocks 0..19 reduce pnrhT column b; 20/21 reduce Zr/Zw
  if(b<20){
    const double* src=pnrhT+(size_t)b*PST;
    double s=0.0;
    for(int idx=t; idx<NB; idx+=256) s+=src[idx];
    dd[t]=s; __syncthreads();
    for(int o=128;o>0;o>>=1){ if(t<o) dd[t]+=dd[t+o]; __syncthreads(); }
    if(t==0) nrhraw[b]=dd[0];
  } else if(b==20||b==21){
    int c=b-20;
    double s=0.0;
    for(int idx=t; idx<NB; idx+=256) s+=pZ[2*idx+c];
    dd[t]=s; __syncthreads();
    for(int o=128;o>0;o>>=1){ if(t<o) dd[t]+=dd[t+o]; __syncthreads(); }
    if(t==0) Sd[c]=dd[0];
  }
  grid.sync();
  // P1: L1 — 220 rows over waves; in40 built per block
  if(t<40){
    in40[t]=(t<20)? rhd[t] : (float)(nrhraw[t-20]/(Sd[0]+1e-16));
  }
  if(b==0 && t<20) out[NRH_OFF+t]=(float)(nrhraw[t]/(Sd[0]+1e-16));
  __syncthreads();
  if(wid<220){
    int net=(wid>=110), r=wid-net*110;
    const float* w=(net?mW1:aW1)+(size_t)r*40;
    float a=(lane<40)? w[lane]*in40[lane] : 0.f;
    for(int off=32;off>0;off>>=1) a+=__shfl_down(a,off,64);
    if(lane==0) h1g[wid]=fmaxf(a+(net?mb1:ab1)[r],0.f);
  }
  grid.sync();
  // P2: L2 — 380 rows, K=110
  if(wid<380){
    int net=(wid>=190), r=wid-net*190;
    const float* w=(net?mW2:aW2)+(size_t)r*110;
    const float* in=h1g+net*110;
    float a=0.f;
    for(int c=lane;c<110;c+=64) a+=w[c]*in[c];
    for(int off=32;off>0;off>>=1) a+=__shfl_down(a,off,64);
    if(lane==0) h2g[wid]=fmaxf(a+(net?mb2:ab2)[r],0.f);
  }
  grid.sync();
  // P3: L3 — 540 rows, K=190
  if(wid<540){
    int net=(wid>=270), r=wid-net*270;
    const float* w=(net?mW3:aW3)+(size_t)r*190;
    const float* in=h2g+net*190;
    float a=0.f;
    for(int c=lane;c<190;c+=64) a+=w[c]*in[c];
    for(int off=32;off>0;off>>=1) a+=__shfl_down(a,off,64);
    if(lane==0) h3g[wid]=fmaxf(a+(net?mb3:ab3)[r],0.f);
  }
  grid.sync();
  // P4: L4 — 650 rows, K=270
  for(int r0=wid; r0<650; r0+=CB*4){
    int net=(r0>=325), r=r0-net*325;
    const float* w=(net?mW4:aW4)+(size_t)r*270;
    const float* in=h3g+net*270;
    float a=0.f;
    for(int c=lane;c<270;c+=64) a+=w[c]*in[c];
    for(int off=32;off>0;off>>=1) a+=__shfl_down(a,off,64);
    if(lane==0) h4g[r0]=a+(net?mb4:ab4)[r];
  }
  grid.sync();
  // P5: fin — blocks 0..20: redundant dual softmax; 0..19 one Wv row; 20 writes out
  if(b<21){
    float a0=h4g[t], a1=(t<69)?h4g[256+t]:-3.0e38f;
    red[t]=fmaxf(a0,a1); __syncthreads();
    for(int o=128;o>0;o>>=1){ if(t<o) red[t]=fmaxf(red[t],red[t+o]); __syncthreads(); }
    if(t==0) sc[0]=red[0]; __syncthreads();
    float ea0=expf(a0-sc[0]), ea1=(t<69)?expf(a1-sc[0]):0.f;
    red[t]=ea0+ea1; __syncthreads();
    for(int o=128;o>0;o>>=1){ if(t<o) red[t]+=red[t+o]; __syncthreads(); }
    if(t==0) sc[1]=red[0]; __syncthreads();
    float sA=sc[1];
    float pA0=ea0/sA, pA1=ea1/sA;
    __syncthreads();
    float m0=h4g[325+t], m1=(t<69)?h4g[325+256+t]:-3.0e38f;
    red[t]=fmaxf(m0,m1); __syncthreads();
    for(int o=128;o>0;o>>=1){ if(t<o) red[t]=fmaxf(red[t],red[t+o]); __syncthreads(); }
    if(t==0) sc[0]=red[0]; __syncthreads();
    float em0=expf(m0-sc[0]), em1=(t<69)?expf(m1-sc[0]):0.f;
    red[t]=em0+em1; __syncthreads();
    for(int o=128;o>0;o>>=1){ if(t<o) red[t]+=red[t+o]; __syncthreads(); }
    if(t==0) sc[1]=red[0]; __syncthreads();
    float sM=sc[1];
    float ah0=P[105], ah1=P[106];
    float ov0=ah0*pA0+ah1*(em0/sM);
    float ov1=(t<69)? ah0*pA1+ah1*(em1/sM) : 0.f;
    if(b==20){
      out[OUT_OFF+t]=ov0;
      if(t<69) out[OUT_OFF+256+t]=ov1;
    } else {
      const float* w=Wv+(size_t)b*325;
      float a=w[t]*ov0;
      if(t<69) a+=w[256+t]*ov1;
      red[t]=a; __syncthreads();
      for(int o=128;o>0;o>>=1){ if(t<o) red[t]+=red[t+o]; __syncthreads(); }
      if(t==0){
        float rho=P[104];
        P[112+b]=rho*P[84+b]+(1.0f-rho)*(red[0]+bv[b]);
      }
    }
  }
}

// ------- K4: normalize rw/ww in place + new_memory -------
__global__ __launch_bounds__(256) void k_memupd(const float* __restrict__ M,
                         float* __restrict__ w_r, float* __restrict__ w_w,
                         const float* __restrict__ P, const double* __restrict__ Sd,
                         float* __restrict__ nm){
  __shared__ float4 ld[1280];
  int t=threadIdx.x, b=blockIdx.x;
  float er[20], af[20];
#pragma unroll
  for(int j=0;j<20;j++){ er[j]=P[64+j]; af[j]=P[112+j]; }
  float Zr=(float)Sd[0]+1e-16f, Zw=(float)Sd[1]+1e-16f;
  const float4* Mf4=(const float4*)M;
  float4* nmf4=(float4*)nm;
  for(int p=0;p<4;p++){
    int rb=b*1024+p*256;
    size_t f4b=(size_t)rb*5;
#pragma unroll
    for(int k=0;k<5;k++){
      size_t idx=f4b+(size_t)(k*256+t);
      if(idx<NF4) ld[k*256+t]=Mf4[idx];
    }
    __syncthreads();
    int i=rb+t;
    if(i<NN){
      float wrn=w_r[i]/Zr;
      float wwn=w_w[i]/Zw;
      w_r[i]=wrn; w_w[i]=wwn;
#pragma unroll
      for(int q=0;q<5;q++){
        float4 v=ld[t*5+q];
        float4 o;
        o.x=v.x*(1.0f-wwn*er[4*q+0])+wwn*af[4*q+0];
        o.y=v.y*(1.0f-wwn*er[4*q+1])+wwn*af[4*q+1];
        o.z=v.z*(1.0f-wwn*er[4*q+2])+wwn*af[4*q+2];
        o.w=v.w*(1.0f-wwn*er[4*q+3])+wwn*af[4*q+3];
        ld[t*5+q]=o;
      }
    }
    __syncthreads();
#pragma unroll
    for(int k=0;k<5;k++){
      size_t idx=f4b+(size_t)(k*256+t);
      if(idx<NF4) nmf4[idx]=ld[k*256+t];
    }
    __syncthreads();
  }
}

extern "C" void kernel_launch(void* const* d_in, const int* in_sizes, int n_in,
                              void* d_out, int out_size, void* d_ws, size_t ws_size,
                              hipStream_t stream) {
  const float* X    =(const float*)d_in[0];
  const float* rwp  =(const float*)d_in[1];
  const float* wwp  =(const float*)d_in[2];
  const float* Mem  =(const float*)d_in[3];
  const float* rhd  =(const float*)d_in[4];
  const float* W1   =(const float*)d_in[5];
  const float* b1   =(const float*)d_in[6];
  const float* W2   =(const float*)d_in[7];
  const float* b2   =(const float*)d_in[8];
  const float* Wxi  =(const float*)d_in[9];
  const float* bxi  =(const float*)d_in[10];
  const float* Wz   =(const float*)d_in[11];
  const float* bz   =(const float*)d_in[12];
  const float* Wv   =(const float*)d_in[13];
  const float* bv   =(const float*)d_in[14];
  const float* aW1  =(const float*)d_in[15];
  const float* ab1  =(const float*)d_in[16];
  const float* aW2  =(const float*)d_in[17];
  const float* ab2  =(const float*)d_in[18];
  const float* aW3  =(const float*)d_in[19];
  const float* ab3  =(const float*)d_in[20];
  const float* aW4  =(const float*)d_in[21];
  const float* ab4  =(const float*)d_in[22];
  const float* mW1  =(const float*)d_in[23];
  const float* mb1  =(const float*)d_in[24];
  const float* mW2  =(const float*)d_in[25];
  const float* mb2  =(const float*)d_in[26];
  const float* mW3  =(const float*)d_in[27];
  const float* mb3  =(const float*)d_in[28];
  const float* mW4  =(const float*)d_in[29];
  const float* mb4  =(const float*)d_in[30];

  float* out = (float*)d_out;
  char* ws = (char*)d_ws;
  float*  P      = (float*)(ws + 0);        // 256 floats
  double* Sd     = (double*)(ws + 2048);    // Z_r, Z_w
  double* nrhraw = (double*)(ws + 2304);    // 20 doubles
  float*  h1g    = (float*)(ws + 4096);     // 220
  float*  h2g    = (float*)(ws + 8192);     // 380
  float*  h3g    = (float*)(ws + 12288);    // 540
  float*  h4g    = (float*)(ws + 16384);    // 650
  float4* pms    = (float4*)(ws + 32768);   // NB float4 (~15.6 KB)
  double* pZ     = (double*)(ws + 65536);   // NB*2 (~15.6 KB)
  double* pnrhT  = (double*)(ws + 131072);  // 20*PST doubles (160 KB)

  float2* sc2 = (float2*)(out + NM_OFF);   // scores staged in dead nm region
  float*  w_r = out + RW_OFF;              // unnormalized until k_memupd
  float*  w_w = out + WW_OFF;
  float*  nm  = out + NM_OFF;

  k_scores<<<NB,256,0,stream>>>(X,W1,b1,W2,b2,Wxi,bxi,Wz,bz,Mem,P,sc2,pms);
  k_shift<<<NB,256,0,stream>>>(sc2,rwp,wwp,Mem,P,pms,w_r,w_w,pZ,pnrhT);
  {
    void* args[] = {
      (void*)&pZ,(void*)&pnrhT,(void*)&rhd,
      (void*)&aW1,(void*)&ab1,(void*)&mW1,(void*)&mb1,
      (void*)&aW2,(void*)&ab2,(void*)&mW2,(void*)&mb2,
      (void*)&aW3,(void*)&ab3,(void*)&mW3,(void*)&mb3,
      (void*)&aW4,(void*)&ab4,(void*)&mW4,(void*)&mb4,
      (void*)&Wv,(void*)&bv,(void*)&P,(void*)&out,
      (void*)&Sd,(void*)&nrhraw,
      (void*)&h1g,(void*)&h2g,(void*)&h3g,(void*)&h4g
    };
    hipLaunchCooperativeKernel((void*)k_coop, dim3(CB), dim3(256), args, 0, stream);
  }
  k_memupd<<<NB,256,0,stream>>>(Mem,w_r,w_w,P,Sd,nm);
}

// Round 11
// 188.963 us; speedup vs baseline: 1.0216x; 1.0216x over previous
//
#include <hip/hip_runtime.h>
#include <math.h>

#define NN 1000000
#define NF4 5000000       // NN*5 float4s in Memory
#define WD 20
#define NB 977            // blocks of 1024 rows
#define PST 1024          // pnrhT column stride

// d_out layout (floats): out[325] | rw[NN] | ww[NN] | new_memory[NN*20] | nrh[20]
#define OUT_OFF 0
#define RW_OFF  325
#define WW_OFF  1000325
#define NM_OFF  2000325
#define NRH_OFF 22000325

typedef unsigned int uint;

__device__ __forceinline__ float sigmoidf_(float x){ return 1.0f/(1.0f+expf(-x)); }
__device__ __forceinline__ float softplusf_(float x){ return (x>30.f)?x:log1pf(expf(x)); }

// ------- K1: head prologue (redundant) + cosine scores + weight prefetch + ticket zero -------
// P layout: kr:0-19 gr:20 sr:21-23 gammar:24 betar:25 knr:26
//           kw:32-51 gw:52 sw:53-55 gammaw:56 betaw:57 knw:58
//           erase:64-83 addraw:84-103 rho:104 ah0:105 ah1:106 addf:112-131
__global__ __launch_bounds__(256) void k_scores(
    const float* __restrict__ X,
    const float* __restrict__ W1, const float* __restrict__ b1,
    const float* __restrict__ W2, const float* __restrict__ b2,
    const float* __restrict__ Wxi, const float* __restrict__ bxi,
    const float* __restrict__ Wz, const float* __restrict__ bz,
    const float* __restrict__ M, float* __restrict__ Pg,
    float2* __restrict__ sc2, float4* __restrict__ pms,
    uint* __restrict__ tk,
    const float* __restrict__ aW1, const float* __restrict__ mW1,
    const float* __restrict__ aW2, const float* __restrict__ mW2,
    const float* __restrict__ aW3, const float* __restrict__ mW3,
    const float* __restrict__ aW4, const float* __restrict__ mW4,
    const float* __restrict__ Wv){
  __shared__ float4 ld[1280];   // 20 KB
  __shared__ float h1[48], h2[72], xi[95], sP[132];
  int t=threadIdx.x, b=blockIdx.x;
  if(b==0 && t<2) tk[t]=0u;
  if(t<48){ float a=b1[t]; const float* w=W1+t*14; for(int c=0;c<14;c++) a+=X[c]*w[c]; h1[t]=a; }
  __syncthreads();
  if(t<72){ float a=b2[t]; const float* w=W2+t*48; for(int c=0;c<48;c++) a+=h1[c]*w[c]; h2[t]=a; }
  __syncthreads();
  if(t<92){ float a=bxi[t]; const float* w=Wxi+t*72; for(int c=0;c<72;c++) a+=h2[c]*w[c]; xi[t]=a; }
  else if(t<95){ int z=t-92; float a=bz[z]; const float* w=Wz+z*72; for(int c=0;c<72;c++) a+=h2[c]*w[c]; xi[92+z]=a; }
  __syncthreads();
  if(t<20){
    sP[0+t]  = tanhf(xi[t]);
    sP[32+t] = tanhf(xi[26+t]);
    sP[64+t] = sigmoidf_(xi[52+t]);
    sP[84+t] = tanhf(xi[72+t]);
  }
  __syncthreads();
  if(t==32){
    float g=sigmoidf_(xi[20]);
    float a0=xi[21],a1=xi[22],a2=xi[23];
    float mx=fmaxf(a0,fmaxf(a1,a2));
    float e0=expf(a0-mx),e1=expf(a1-mx),e2=expf(a2-mx),es=e0+e1+e2;
    float gamma=1.0f+softplusf_(xi[24]);
    float beta=softplusf_(xi[25]);
    float n2=0.f;
#pragma unroll
    for(int j=0;j<20;j++){ float ke=sP[j]+1e-16f; n2+=ke*ke; }
    sP[20]=g; sP[21]=e0/es; sP[22]=e1/es; sP[23]=e2/es; sP[24]=gamma; sP[25]=beta;
    sP[26]=fmaxf(sqrtf(n2),1e-8f);
  }
  if(t==96){
    float g=sigmoidf_(xi[46]);
    float a0=xi[47],a1=xi[48],a2=xi[49];
    float mx=fmaxf(a0,fmaxf(a1,a2));
    float e0=expf(a0-mx),e1=expf(a1-mx),e2=expf(a2-mx),es=e0+e1+e2;
    float gamma=1.0f+softplusf_(xi[50]);
    float beta=softplusf_(xi[51]);
    float n2=0.f;
#pragma unroll
    for(int j=0;j<20;j++){ float ke=sP[32+j]+1e-16f; n2+=ke*ke; }
    sP[52]=g; sP[53]=e0/es; sP[54]=e1/es; sP[55]=e2/es; sP[56]=gamma; sP[57]=beta;
    sP[58]=fmaxf(sqrtf(n2),1e-8f);
  }
  if(t==160){
    sP[104]=sigmoidf_(xi[92]);
    float mx=fmaxf(xi[93],xi[94]);
    float e1=expf(xi[93]-mx), e2=expf(xi[94]-mx);
    sP[105]=e1/(e1+e2); sP[106]=e2/(e1+e2);
  }
  __syncthreads();
  if(b==0 && t<132) Pg[t]=sP[t];
  // weight prefetch to L2/L3 (blocks 100-199, dummy-consumed)
  if(b>=100 && b<200){
    int pid=(b-100)*256+t;   // 0..25599
    float pf=0.f;
    const float4* a4;
    a4=(const float4*)aW1; for(int i=pid;i<1100;i+=25600)  pf+=a4[i].x;
    a4=(const float4*)mW1; for(int i=pid;i<1100;i+=25600)  pf+=a4[i].x;
    a4=(const float4*)aW2; for(int i=pid;i<5225;i+=25600)  pf+=a4[i].x;
    a4=(const float4*)mW2; for(int i=pid;i<5225;i+=25600)  pf+=a4[i].x;
    a4=(const float4*)aW3; for(int i=pid;i<12825;i+=25600) pf+=a4[i].x;
    a4=(const float4*)mW3; for(int i=pid;i<12825;i+=25600) pf+=a4[i].x;
    a4=(const float4*)aW4; for(int i=pid;i<21937;i+=25600) pf+=a4[i].x;
    a4=(const float4*)mW4; for(int i=pid;i<21937;i+=25600) pf+=a4[i].x;
    a4=(const float4*)Wv;  for(int i=pid;i<1625;i+=25600)  pf+=a4[i].x;
    if(pf==12345.678f) Pg[255]=pf;
  }
  float kr[20], kw[20];
#pragma unroll
  for(int j=0;j<20;j++){ kr[j]=sP[j]+1e-16f; kw[j]=sP[32+j]+1e-16f; }
  float betar=sP[25], betaw=sP[57], knr=sP[26], knw=sP[58];
  const float4* Mf4=(const float4*)M;
  float sR[4], sW[4];
  for(int p=0;p<4;p++){
    int rb=b*1024+p*256;
    size_t f4b=(size_t)rb*5;
#pragma unroll
    for(int k=0;k<5;k++){
      size_t idx=f4b+(size_t)(k*256+t);
      ld[k*256+t] = (idx<NF4)?Mf4[idx]:make_float4(0.f,0.f,0.f,0.f);
    }
    __syncthreads();
    int i=rb+t;
    float srv=-3.0e38f, swv=-3.0e38f;
    if(i<NN){
      float dr=0.f,dw=0.f,n2=0.f;
#pragma unroll
      for(int q=0;q<5;q++){
        float4 v=ld[t*5+q];
        float m0=v.x+1e-16f,m1=v.y+1e-16f,m2=v.z+1e-16f,m3=v.w+1e-16f;
        dr+=m0*kr[4*q]+m1*kr[4*q+1]+m2*kr[4*q+2]+m3*kr[4*q+3];
        dw+=m0*kw[4*q]+m1*kw[4*q+1]+m2*kw[4*q+2]+m3*kw[4*q+3];
        n2+=m0*m0+m1*m1+m2*m2+m3*m3;
      }
      float nm=fmaxf(sqrtf(n2),1e-8f);
      srv=betar*(dr/(nm*knr));
      swv=betaw*(dw/(nm*knw));
      sc2[i]=make_float2(srv,swv);
    }
    sR[p]=srv; sW[p]=swv;
    __syncthreads();
  }
  float* r1=(float*)ld; float* r2=r1+256;
  double* d1=(double*)(r1+512); double* d2=d1+256;
  float lm1=fmaxf(fmaxf(sR[0],sR[1]),fmaxf(sR[2],sR[3]));
  float lm2=fmaxf(fmaxf(sW[0],sW[1]),fmaxf(sW[2],sW[3]));
  r1[t]=lm1; r2[t]=lm2; __syncthreads();
  for(int o=128;o>0;o>>=1){ if(t<o){ r1[t]=fmaxf(r1[t],r1[t+o]); r2[t]=fmaxf(r2[t],r2[t+o]); } __syncthreads(); }
  float mb1=r1[0], mb2=r2[0]; __syncthreads();
  double s1=0.0,s2=0.0;
#pragma unroll
  for(int p=0;p<4;p++){ s1+=(double)expf(sR[p]-mb1); s2+=(double)expf(sW[p]-mb2); }
  d1[t]=s1; d2[t]=s2; __syncthreads();
  for(int o=128;o>0;o>>=1){ if(t<o){ d1[t]+=d1[t+o]; d2[t]+=d2[t+o]; } __syncthreads(); }
  if(t==0) pms[b]=make_float4(mb1,mb2,(float)d1[0],(float)d2[0]);
}

// ------- K2: shift+pow + fused rw@M; last-arriving block reduces partials -------
__global__ __launch_bounds__(256) void k_shift(const float2* __restrict__ sc2,
                        const float* __restrict__ wpr, const float* __restrict__ wpw,
                        const float* __restrict__ M, const float* __restrict__ P,
                        const float4* __restrict__ pms,
                        const float* __restrict__ read_head,
                        float* __restrict__ w_r_out, float* __restrict__ w_w_out,
                        double* __restrict__ pZ, double* __restrict__ pnrhT,
                        double* __restrict__ Sd, float* __restrict__ in40g,
                        float* __restrict__ out, uint* __restrict__ tk){
  __shared__ float4 ld[1280];
  __shared__ float bmS[4];
  __shared__ int lastFlag;
  __shared__ double colr[22];
  float* r1=(float*)ld; float* r2=r1+256;
  double* d1=(double*)(r1+512); double* d2=d1+256;
  float* wsum=(float*)(d2+256);  // [4][20]
  int t=threadIdx.x, b=blockIdx.x;
  float4 v4[4];
#pragma unroll
  for(int k=0;k<4;k++){
    int idx=t+k*256;
    v4[k] = (idx<NB) ? pms[idx] : make_float4(-3.0e38f,-3.0e38f,0.f,0.f);
  }
  float lm1=fmaxf(fmaxf(v4[0].x,v4[1].x),fmaxf(v4[2].x,v4[3].x));
  float lm2=fmaxf(fmaxf(v4[0].y,v4[1].y),fmaxf(v4[2].y,v4[3].y));
  r1[t]=lm1; r2[t]=lm2; __syncthreads();
  for(int o=128;o>0;o>>=1){ if(t<o){ r1[t]=fmaxf(r1[t],r1[t+o]); r2[t]=fmaxf(r2[t],r2[t+o]); } __syncthreads(); }
  if(t==0){ bmS[0]=r1[0]; bmS[1]=r2[0]; } __syncthreads();
  float mr=bmS[0], mw=bmS[1];
  double s1=0.0,s2=0.0;
#pragma unroll
  for(int k=0;k<4;k++){
    s1 += (double)v4[k].z * (double)expf(v4[k].x-mr);
    s2 += (double)v4[k].w * (double)expf(v4[k].y-mw);
  }
  d1[t]=s1; d2[t]=s2; __syncthreads();
  for(int o=128;o>0;o>>=1){ if(t<o){ d1[t]+=d1[t+o]; d2[t]+=d2[t+o]; } __syncthreads(); }
  if(t==0){ bmS[2]=(float)d1[0]; bmS[3]=(float)d2[0]; } __syncthreads();
  float Sr=bmS[2], Sw=bmS[3];
  float gr=P[20], s0r=P[21], s1r=P[22], s2r=P[23], gar=P[24];
  float gw=P[52], s0w=P[53], s1w=P[54], s2w=P[55], gaw=P[56];
  float omgr=1.0f-gr, omgw=1.0f-gw;
  const float4* Mf4=(const float4*)M;
  float acc[20];
#pragma unroll
  for(int j=0;j<20;j++) acc[j]=0.f;
  double zr=0.0, zw=0.0;
  for(int p=0;p<4;p++){
    int rb=b*1024+p*256;
    size_t f4b=(size_t)rb*5;
#pragma unroll
    for(int k=0;k<5;k++){
      size_t idx=f4b+(size_t)(k*256+t);
      ld[k*256+t] = (idx<NF4)?Mf4[idx]:make_float4(0.f,0.f,0.f,0.f);
    }
    __syncthreads();
    int i=rb+t;
    if(i<NN){
      int im1=(i==0)?(NN-1):(i-1);
      int ip1=(i==NN-1)?0:(i+1);
      float2 scm=sc2[im1], sc0=sc2[i], scp=sc2[ip1];
      float wgrm = gr*(expf(scm.x-mr)/Sr) + omgr*wpr[im1];
      float wgr0 = gr*(expf(sc0.x-mr)/Sr) + omgr*wpr[i  ];
      float wgrp = gr*(expf(scp.x-mr)/Sr) + omgr*wpr[ip1];
      float wgwm = gw*(expf(scm.y-mw)/Sw) + omgw*wpw[im1];
      float wgw0 = gw*(expf(sc0.y-mw)/Sw) + omgw*wpw[i  ];
      float wgwp = gw*(expf(scp.y-mw)/Sw) + omgw*wpw[ip1];
      float wr = powf(s0r*wgrm + s1r*wgr0 + s2r*wgrp, gar);
      float ww = powf(s0w*wgwm + s1w*wgw0 + s2w*wgwp, gaw);
      w_r_out[i]=wr; w_w_out[i]=ww;
      zr+=(double)wr; zw+=(double)ww;
#pragma unroll
      for(int q=0;q<5;q++){
        float4 mv=ld[t*5+q];
        acc[4*q+0]+=wr*mv.x; acc[4*q+1]+=wr*mv.y; acc[4*q+2]+=wr*mv.z; acc[4*q+3]+=wr*mv.w;
      }
    }
    __syncthreads();
  }
  d1[t]=zr; d2[t]=zw; __syncthreads();
  for(int o=128;o>0;o>>=1){ if(t<o){ d1[t]+=d1[t+o]; d2[t]+=d2[t+o]; } __syncthreads(); }
  if(t==0){ pZ[2*b]=d1[0]; pZ[2*b+1]=d2[0]; }
  __syncthreads();
#pragma unroll
  for(int j=0;j<20;j++){
    for(int off=32;off>0;off>>=1) acc[j]+=__shfl_down(acc[j],off,64);
  }
  int wave=t>>6, lane=t&63;
  if(lane==0){
#pragma unroll
    for(int j=0;j<20;j++) wsum[wave*20+j]=acc[j];
  }
  __syncthreads();
  if(t<20){
    double s=(double)wsum[0*20+t]+(double)wsum[1*20+t]+(double)wsum[2*20+t]+(double)wsum[3*20+t];
    pnrhT[(size_t)t*PST+b]=s;
  }
  // ---- ticket: last-arriving block reduces all partials ----
  __syncthreads();
  if(t==0){
    __threadfence();
    uint old=__hip_atomic_fetch_add(tk,1u,__ATOMIC_ACQ_REL,__HIP_MEMORY_SCOPE_AGENT);
    lastFlag=(old==NB-1);
  }
  __syncthreads();
  if(lastFlag){
    __threadfence();
    for(int j=wave;j<22;j+=4){
      double s=0.0;
      if(j<20){
        const double* src=pnrhT+(size_t)j*PST;
        for(int idx=lane;idx<NB;idx+=64) s+=src[idx];
      } else {
        int c=j-20;
        for(int idx=lane;idx<NB;idx+=64) s+=pZ[2*idx+c];
      }
      for(int off=32;off>0;off>>=1) s+=__shfl_down(s,off,64);
      if(lane==0) colr[j]=s;
    }
    __syncthreads();
    if(t<20){
      double Zr=colr[20]+1e-16;
      float nv=(float)(colr[t]/Zr);
      in40g[20+t]=nv; in40g[t]=read_head[t];
      out[NRH_OFF+t]=nv;
    }
    if(t==20){ Sd[0]=colr[20]; Sd[1]=colr[21]; }
  }
}

// ------- K3: redundant L1 (own net) + distributed L2 -------
__global__ __launch_bounds__(256) void k_l12(const float* __restrict__ in40g,
    const float* __restrict__ aW1,const float* __restrict__ ab1,
    const float* __restrict__ mW1,const float* __restrict__ mb1,
    const float* __restrict__ aW2,const float* __restrict__ ab2,
    const float* __restrict__ mW2,const float* __restrict__ mb2,
    float* __restrict__ h2g){
  __shared__ float in40[40], h1s[110];
  int t=threadIdx.x, b=blockIdx.x, wave=t>>6, lane=t&63;
  int net=(b>=48);
  if(t<40) in40[t]=in40g[t];
  __syncthreads();
  int g=t>>4, l16=t&15;
  const float* W1=net?mW1:aW1; const float* B1=net?mb1:ab1;
  for(int pass=0; pass<7; ++pass){
    int r=pass*16+g;
    if(r<110){
      const float* w=W1+(size_t)r*40;
      float a=0.f;
      for(int c=l16;c<40;c+=16) a+=w[c]*in40[c];
      a+=__shfl_xor(a,8,64); a+=__shfl_xor(a,4,64); a+=__shfl_xor(a,2,64); a+=__shfl_xor(a,1,64);
      if(l16==0) h1s[r]=fmaxf(a+B1[r],0.f);
    }
  }
  __syncthreads();
  int r=(b-net*48)*4+wave;
  if(r<190){
    const float* w=(net?mW2:aW2)+(size_t)r*110;
    float a=0.f;
    for(int c=lane;c<110;c+=64) a+=w[c]*h1s[c];
    for(int off=32;off>0;off>>=1) a+=__shfl_down(a,off,64);
    if(lane==0) h2g[net*190+r]=fmaxf(a+(net?mb2:ab2)[r],0.f);
  }
}

// ------- K4: L3 distributed -------
__global__ __launch_bounds__(256) void k_l3(const float* __restrict__ h2g,
    const float* __restrict__ aW3,const float* __restrict__ ab3,
    const float* __restrict__ mW3,const float* __restrict__ mb3,
    float* __restrict__ h3g){
  int t=threadIdx.x, b=blockIdx.x, wave=t>>6, lane=t&63;
  int net=(b>=68);
  int r=(b-net*68)*4+wave;
  if(r>=270) return;
  const float* w=(net?mW3:aW3)+(size_t)r*190;
  const float* in=h2g+net*190;
  float a=0.f;
  for(int c=lane;c<190;c+=64) a+=w[c]*in[c];
  for(int off=32;off>0;off>>=1) a+=__shfl_down(a,off,64);
  if(lane==0) h3g[net*270+r]=fmaxf(a+(net?mb3:ab3)[r],0.f);
}

// ------- K5: L4 distributed; last-arriving block runs fin -------
__global__ __launch_bounds__(256) void k_l4fin(const float* __restrict__ h3g,
    const float* __restrict__ aW4,const float* __restrict__ ab4,
    const float* __restrict__ mW4,const float* __restrict__ mb4,
    const float* __restrict__ Wv, const float* __restrict__ bv,
    float* __restrict__ h4g, float* __restrict__ P, float* __restrict__ out,
    uint* __restrict__ tk){
  __shared__ float red[256], outv[325], sc[2];
  __shared__ int lastFlag;
  int t=threadIdx.x, b=blockIdx.x, wave=t>>6, lane=t&63;
  int wid=b*4+wave;
  if(wid<650){
    int net=(wid>=325), r=wid-net*325;
    const float* w=(net?mW4:aW4)+(size_t)r*270;
    const float* in=h3g+net*270;
    float a=0.f;
    for(int c=lane;c<270;c+=64) a+=w[c]*in[c];
    for(int off=32;off>0;off>>=1) a+=__shfl_down(a,off,64);
    if(lane==0) h4g[wid]=a+(net?mb4:ab4)[r];
  }
  __syncthreads();
  if(t==0){
    __threadfence();
    uint old=__hip_atomic_fetch_add(tk,1u,__ATOMIC_ACQ_REL,__HIP_MEMORY_SCOPE_AGENT);
    lastFlag=(old==163u);
  }
  __syncthreads();
  if(!lastFlag) return;
  __threadfence();
  // fin: dual softmax, combine, out, v, add_final
  float a0=h4g[t], a1=(t<69)?h4g[256+t]:-3.0e38f;
  red[t]=fmaxf(a0,a1); __syncthreads();
  for(int o=128;o>0;o>>=1){ if(t<o) red[t]=fmaxf(red[t],red[t+o]); __syncthreads(); }
  if(t==0) sc[0]=red[0]; __syncthreads();
  float ea0=expf(a0-sc[0]), ea1=(t<69)?expf(a1-sc[0]):0.f;
  red[t]=ea0+ea1; __syncthreads();
  for(int o=128;o>0;o>>=1){ if(t<o) red[t]+=red[t+o]; __syncthreads(); }
  if(t==0) sc[1]=red[0]; __syncthreads();
  float sA=sc[1];
  float pA0=ea0/sA, pA1=ea1/sA;
  __syncthreads();
  float m0=h4g[325+t], m1=(t<69)?h4g[325+256+t]:-3.0e38f;
  red[t]=fmaxf(m0,m1); __syncthreads();
  for(int o=128;o>0;o>>=1){ if(t<o) red[t]=fmaxf(red[t],red[t+o]); __syncthreads(); }
  if(t==0) sc[0]=red[0]; __syncthreads();
  float em0=expf(m0-sc[0]), em1=(t<69)?expf(m1-sc[0]):0.f;
  red[t]=em0+em1; __syncthreads();
  for(int o=128;o>0;o>>=1){ if(t<o) red[t]+=red[t+o]; __syncthreads(); }
  if(t==0) sc[1]=red[0]; __syncthreads();
  float sM=sc[1];
  float ah0=P[105], ah1=P[106];
  float ov0=ah0*pA0+ah1*(em0/sM);
  outv[t]=ov0; out[OUT_OFF+t]=ov0;
  if(t<69){ float ov1=ah0*pA1+ah1*(em1/sM); outv[256+t]=ov1; out[OUT_OFF+256+t]=ov1; }
  __syncthreads();
  float rho=P[104];
  for(int r=wave; r<20; r+=4){
    const float* w=Wv+(size_t)r*325;
    float a=0.f;
    for(int c=lane;c<325;c+=64) a+=w[c]*outv[c];
    for(int off=32;off>0;off>>=1) a+=__shfl_down(a,off,64);
    if(lane==0) P[112+r]=rho*P[84+r]+(1.0f-rho)*(a+bv[r]);
  }
}

// ------- K6: normalize rw/ww in place + new_memory -------
__global__ __launch_bounds__(256) void k_memupd(const float* __restrict__ M,
                         float* __restrict__ w_r, float* __restrict__ w_w,
                         const float* __restrict__ P, const double* __restrict__ Sd,
                         float* __restrict__ nm){
  __shared__ float4 ld[1280];
  int t=threadIdx.x, b=blockIdx.x;
  float er[20], af[20];
#pragma unroll
  for(int j=0;j<20;j++){ er[j]=P[64+j]; af[j]=P[112+j]; }
  float Zr=(float)Sd[0]+1e-16f, Zw=(float)Sd[1]+1e-16f;
  const float4* Mf4=(const float4*)M;
  float4* nmf4=(float4*)nm;
  for(int p=0;p<4;p++){
    int rb=b*1024+p*256;
    size_t f4b=(size_t)rb*5;
#pragma unroll
    for(int k=0;k<5;k++){
      size_t idx=f4b+(size_t)(k*256+t);
      if(idx<NF4) ld[k*256+t]=Mf4[idx];
    }
    __syncthreads();
    int i=rb+t;
    if(i<NN){
      float wrn=w_r[i]/Zr;
      float wwn=w_w[i]/Zw;
      w_r[i]=wrn; w_w[i]=wwn;
#pragma unroll
      for(int q=0;q<5;q++){
        float4 v=ld[t*5+q];
        float4 o;
        o.x=v.x*(1.0f-wwn*er[4*q+0])+wwn*af[4*q+0];
        o.y=v.y*(1.0f-wwn*er[4*q+1])+wwn*af[4*q+1];
        o.z=v.z*(1.0f-wwn*er[4*q+2])+wwn*af[4*q+2];
        o.w=v.w*(1.0f-wwn*er[4*q+3])+wwn*af[4*q+3];
        ld[t*5+q]=o;
      }
    }
    __syncthreads();
#pragma unroll
    for(int k=0;k<5;k++){
      size_t idx=f4b+(size_t)(k*256+t);
      if(idx<NF4) nmf4[idx]=ld[k*256+t];
    }
    __syncthreads();
  }
}

extern "C" void kernel_launch(void* const* d_in, const int* in_sizes, int n_in,
                              void* d_out, int out_size, void* d_ws, size_t ws_size,
                              hipStream_t stream) {
  const float* X    =(const float*)d_in[0];
  const float* rwp  =(const float*)d_in[1];
  const float* wwp  =(const float*)d_in[2];
  const float* Mem  =(const float*)d_in[3];
  const float* rhd  =(const float*)d_in[4];
  const float* W1   =(const float*)d_in[5];
  const float* b1   =(const float*)d_in[6];
  const float* W2   =(const float*)d_in[7];
  const float* b2   =(const float*)d_in[8];
  const float* Wxi  =(const float*)d_in[9];
  const float* bxi  =(const float*)d_in[10];
  const float* Wz   =(const float*)d_in[11];
  const float* bz   =(const float*)d_in[12];
  const float* Wv   =(const float*)d_in[13];
  const float* bv   =(const float*)d_in[14];
  const float* aW1  =(const float*)d_in[15];
  const float* ab1  =(const float*)d_in[16];
  const float* aW2  =(const float*)d_in[17];
  const float* ab2  =(const float*)d_in[18];
  const float* aW3  =(const float*)d_in[19];
  const float* ab3  =(const float*)d_in[20];
  const float* aW4  =(const float*)d_in[21];
  const float* ab4  =(const float*)d_in[22];
  const float* mW1  =(const float*)d_in[23];
  const float* mb1  =(const float*)d_in[24];
  const float* mW2  =(const float*)d_in[25];
  const float* mb2  =(const float*)d_in[26];
  const float* mW3  =(const float*)d_in[27];
  const float* mb3  =(const float*)d_in[28];
  const float* mW4  =(const float*)d_in[29];
  const float* mb4  =(const float*)d_in[30];

  float* out = (float*)d_out;
  char* ws = (char*)d_ws;
  float*  P     = (float*)(ws + 0);        // 256 floats
  double* Sd    = (double*)(ws + 2048);    // Z_r, Z_w
  float*  in40g = (float*)(ws + 2304);     // 40 floats
  uint*   tk    = (uint*)(ws + 2560);      // 2 tickets
  float*  h2g   = (float*)(ws + 4096);     // 380
  float*  h3g   = (float*)(ws + 8192);     // 540
  float*  h4g   = (float*)(ws + 12288);    // 650
  float4* pms   = (float4*)(ws + 32768);   // NB float4 (~15.6 KB)
  double* pZ    = (double*)(ws + 65536);   // NB*2 (~15.6 KB)
  double* pnrhT = (double*)(ws + 131072);  // 20*PST doubles (160 KB)

  float2* sc2 = (float2*)(out + NM_OFF);   // scores staged in dead nm region
  float*  w_r = out + RW_OFF;              // unnormalized until k_memupd
  float*  w_w = out + WW_OFF;
  float*  nm  = out + NM_OFF;

  k_scores<<<NB,256,0,stream>>>(X,W1,b1,W2,b2,Wxi,bxi,Wz,bz,Mem,P,sc2,pms,tk,
                                aW1,mW1,aW2,mW2,aW3,mW3,aW4,mW4,Wv);
  k_shift<<<NB,256,0,stream>>>(sc2,rwp,wwp,Mem,P,pms,rhd,w_r,w_w,pZ,pnrhT,
                               Sd,in40g,out,tk);
  k_l12<<<96,256,0,stream>>>(in40g,aW1,ab1,mW1,mb1,aW2,ab2,mW2,mb2,h2g);
  k_l3<<<136,256,0,stream>>>(h2g,aW3,ab3,mW3,mb3,h3g);
  k_l4fin<<<164,256,0,stream>>>(h3g,aW4,ab4,mW4,mb4,Wv,bv,h4g,P,out,tk+1);
  k_memupd<<<NB,256,0,stream>>>(Mem,w_r,w_w,P,Sd,nm);
}